// Round 3
// baseline (703.646 us; speedup 1.0000x reference)
//
#include <hip/hip_runtime.h>
#include <math.h>
#include <float.h>

#define NL     64
#define NOBS   400
#define NC     3000
#define CHUNK  128
#define NCHUNK 24            // 24*128 = 3072 >= 3000 grid pts + 1 sentinel
#define TWO_PI_F   6.2831853071795864769f
#define INV_2PI_F  0.15915494309189535f
#define LOG2E_F    1.4426950408889634f
#define LOG2_0P1  -3.3219280948873623f

__device__ __forceinline__ float hsin(float x)  { return __builtin_amdgcn_sinf(x); }   // arg pre-scaled by 1/2pi
__device__ __forceinline__ float hcos(float x)  { return __builtin_amdgcn_cosf(x); }
__device__ __forceinline__ float hexp2(float x) { return __builtin_amdgcn_exp2f(x); }
__device__ __forceinline__ float hrcp(float x)  { return __builtin_amdgcn_rcpf(x); }
__device__ __forceinline__ float hsqrt(float x) { return __builtin_amdgcn_sqrtf(x); }

// monotone float <-> uint encoding for atomic max/min
__device__ __forceinline__ unsigned enc(float f) {
    unsigned u = __float_as_uint(f);
    return (u & 0x80000000u) ? ~u : (u | 0x80000000u);
}
__device__ __forceinline__ float dec(unsigned k) {
    unsigned u = (k & 0x80000000u) ? (k & 0x7fffffffu) : ~k;
    return __uint_as_float(u);
}

// ---------------------------------------------------------------------------
// Kernel 1: Brocher b->(a,rho) + init atomic slots
// ---------------------------------------------------------------------------
__global__ void prep_kernel(const float* __restrict__ b, float* __restrict__ a_out,
                            float* __restrict__ rho_out,
                            unsigned* __restrict__ maxenc, unsigned* __restrict__ minenc) {
    int i = threadIdx.x;   // 256 threads
    if (i < NL) {
        float bb = b[i];
        float b2 = bb * bb, b3 = b2 * bb, b4 = b3 * bb;
        float a = 0.9409f + 2.0947f * bb - 0.8206f * b2 + 0.2683f * b3 - 0.0251f * b4;
        float a2 = a * a, a3 = a2 * a, a4 = a3 * a, a5 = a4 * a;
        float rho = 1.6612f * a - 0.4721f * a2 + 0.0671f * a3 - 0.0043f * a4 + 0.000106f * a5;
        a_out[i] = a;
        rho_out[i] = rho;
    }
    for (int j = i; j < NOBS; j += 256) {
        maxenc[j] = 0u;            // below enc of any finite float
        minenc[j] = 0xFFFFFFFFu;   // above enc of any finite float
    }
}

// ---------------------------------------------------------------------------
// One Dunkin layer step. P points to this layer's 16-float LDS record:
// [xka, xkb, gammk, dm, dms(dm/2pi), dme(-2*log2e*dm), rm, irm, rho2, irho2]
// ---------------------------------------------------------------------------
template <bool NORM>
__device__ __forceinline__ void layer_step(
    float& e0, float& e1, float& e2, float& e3, float& e4,
    const float* __restrict__ P,
    float wvno, float wvno2, float wvno4, float t2, float w2x2) {

    float xka = P[0], xkb = P[1], gammk = P[2], dm = P[3];
    float dms = P[4], dme = P[5], rm = P[6], irm = P[7];
    float rho2 = P[8], irho2 = P[9];

    float ra = hsqrt((wvno + xka) * fabsf(wvno - xka));
    float rb = hsqrt((wvno + xkb) * fabsf(wvno - xkb));
    float gam = gammk * wvno2;
    float p = ra * dm, q = rb * dm;

    float ra_s = (ra > 0.0f) ? ra : 1.0f;
    float rb_s = (rb > 0.0f) ? rb : 1.0f;
    float rp  = hrcp(ra_s * rb_s);
    float ira = rb_s * rp;
    float irb = ra_s * rp;

    float sinp = hsin(ra * dms);
    float cospt = hcos(ra * dms);
    float facp = hexp2(ra * dme);
    float sinq = hsin(rb * dms);
    float cosqt = hcos(rb * dms);
    float facq = hexp2(rb * dme);

    bool ltp = wvno < xka;
    bool lts = wvno < xkb;
    float sinp_e = 0.5f - 0.5f * facp;
    float sinq_e = 0.5f - 0.5f * facq;
    float pex = ltp ? 0.0f : p;
    float sex = lts ? 0.0f : q;
    float cosp = ltp ? cospt : (0.5f + 0.5f * facp);
    float cosq = lts ? cosqt : (0.5f + 0.5f * facq);
    float w = (ltp ? sinp : sinp_e) * ira;
    float x = ra * (ltp ? -sinp : sinp_e);
    float y = (lts ? sinq : sinq_e) * irb;
    float z = rb * (lts ? -sinq : sinq_e);
    float a0 = hexp2(-LOG2E_F * (pex + sex));

    float cpcq = cosp * cosq;
    float cpy = cosp * y, cpz = cosp * z;
    float cqw = cosq * w, cqx = cosq * x;
    float xy = x * y, xz = x * z, wy = w * y, wz = w * z;

    float gamm1 = gam - 1.0f;
    float twgm1 = gam + gamm1;
    float gmgmk = gam * gammk;
    float gmgm1 = gam * gamm1;
    float gm1sq = gamm1 * gamm1;
    float a0pq  = a0 - cpcq;

    float c00 = cpcq - 2.0f * gmgm1 * a0pq - gmgmk * xz - wvno2 * gm1sq * wy;
    float c01 = (wvno2 * cpy - cqx) * irm;
    float c02 = -(twgm1 * a0pq + gammk * xz + wvno2 * gamm1 * wy) * irm;
    float c03 = (cpz - wvno2 * cqw) * irm;
    float c04 = -(w2x2 * a0pq + xz + wvno4 * wy) * irho2;
    float c10 = (gmgmk * cpz - gm1sq * cqw) * rm;
    float c12 = gammk * cpz - gamm1 * cqw;
    float c30 = (gm1sq * cpy - gmgmk * cqx) * rm;
    float c32 = gamm1 * cpy - gammk * cqx;
    float q1  = gmgmk * gm1sq;
    float c40 = -(2.0f * q1 * a0pq + gmgmk * gmgmk * xz + gm1sq * gm1sq * wy) * rho2;
    float c42 = -(gmgm1 * twgm1 * a0pq + gmgmk * gammk * xz + gamm1 * gm1sq * wy) * rm;
    float c22 = a0 + 2.0f * (cpcq - c00);

    float e2t = e2 * t2;   // row 2 of ca = t2 * {c42, c32, -, c12, c02}

    float ee0 = e0 * c00 + e1 * c10 + e2t * c42 + e3 * c30 + e4 * c40;
    float ee1 = e0 * c01 + e1 * cpcq + e2t * c32 - e3 * xy + e4 * c30;
    float ee2 = e0 * c02 + e1 * c12 + e2 * c22 + e3 * c32 + e4 * c42;
    float ee3 = e0 * c03 - e1 * wz + e2t * c12 + e3 * cpcq + e4 * c10;
    float ee4 = e0 * c04 + e1 * c03 + e2t * c02 + e3 * c01 + e4 * c00;

    if (NORM) {
        float nrm = fmaxf(fmaxf(fmaxf(fabsf(ee0), fabsf(ee1)),
                                fmaxf(fabsf(ee2), fabsf(ee3))), fabsf(ee4));
        nrm = fmaxf(nrm, 1e-30f);
        float inv = hrcp(nrm);
        e0 = ee0 * inv; e1 = ee1 * inv; e2 = ee2 * inv; e3 = ee3 * inv; e4 = ee4 * inv;
    } else {
        e0 = ee0; e1 = ee1; e2 = ee2; e3 = ee3; e4 = ee4;
    }
}

__device__ float det_eval(float cvel, float omega, const float* __restrict__ Lf) {
    float wvno  = omega * hrcp(cvel);
    float wvno2 = wvno * wvno;
    float wvno4 = wvno2 * wvno2;
    float t2    = -2.0f * wvno2;
    float w2x2  = 2.0f * wvno2;

    // halfspace (layer NL-1)
    const float* P = &Lf[(NL - 1) * 16];
    float xka = P[0], xkb = P[1], gammk = P[2], r = P[6];
    float ra = hsqrt((wvno + xka) * fabsf(wvno - xka));
    float rb = hsqrt((wvno + xkb) * fabsf(wvno - xkb));
    float gam = gammk * wvno2;
    float gamm1 = gam - 1.0f;
    float rarb = ra * rb;

    float e0 = r * r * (gamm1 * gamm1 - gam * gammk * rarb);
    float e1 = -r * ra;
    float e2 = r * (gamm1 - gammk * rarb);
    float e3 = r * rb;
    float e4 = wvno2 - rarb;

    // 63 layers: pairs (62,61)...(2,1) with norm on 2nd of each, then 0 (norm).
    #pragma unroll 1
    for (int m = NL - 2; m >= 2; m -= 2) {
        layer_step<false>(e0, e1, e2, e3, e4, &Lf[m * 16], wvno, wvno2, wvno4, t2, w2x2);
        layer_step<true >(e0, e1, e2, e3, e4, &Lf[(m - 1) * 16], wvno, wvno2, wvno4, t2, w2x2);
    }
    layer_step<true>(e0, e1, e2, e3, e4, &Lf[0], wvno, wvno2, wvno4, t2, w2x2);
    return e0;
}

// ---------------------------------------------------------------------------
// Kernel 2: one det per thread; wave-reduce max/min; atomics per wave.
// grid = (NCHUNK, NOBS), block = 128. idx==NC is the (vlist[t],tlist[t]) sentinel.
// ---------------------------------------------------------------------------
__global__ __launch_bounds__(128, 8) void det_kernel(
    const float* __restrict__ vlist, const float* __restrict__ tlist,
    const float* __restrict__ d, const float* __restrict__ b,
    const float* __restrict__ Clist,
    const float* __restrict__ a_arr, const float* __restrict__ rho_arr,
    unsigned* __restrict__ maxenc, unsigned* __restrict__ minenc,
    float* __restrict__ e00vals) {

    __shared__ float Lf[NL * 16];

    int t     = blockIdx.y;
    int chunk = blockIdx.x;
    int tid   = threadIdx.x;

    float omega = fmaxf(TWO_PI_F / tlist[t], 0.0001f);

    if (tid < NL) {
        float am = a_arr[tid];
        float bm = b[tid];
        float rm = rho_arr[tid];
        float dm = d[tid];
        float* P = &Lf[tid * 16];
        P[0] = omega / am;
        P[1] = omega / bm;
        float tt = bm / omega;
        P[2] = 2.0f * tt * tt;
        P[3] = dm;
        P[4] = dm * INV_2PI_F;
        P[5] = -2.0f * LOG2E_F * dm;
        P[6] = rm;
        P[7] = 1.0f / rm;
        P[8] = rm * rm;
        P[9] = 1.0f / (rm * rm);
    }
    __syncthreads();

    int idx = chunk * CHUNK + tid;
    float lmax = -FLT_MAX, lmin = FLT_MAX;

    if (idx <= NC) {
        bool grid_pt = idx < NC;
        float cvel = grid_pt ? Clist[idx] : vlist[t];
        float det  = det_eval(cvel, omega, Lf);
        if (grid_pt) {
            lmax = det;
            lmin = det;
        } else {
            e00vals[t] = det;
        }
    }

    // wave-level butterfly reduce (64 lanes)
    #pragma unroll
    for (int off = 32; off >= 1; off >>= 1) {
        lmax = fmaxf(lmax, __shfl_xor(lmax, off));
        lmin = fminf(lmin, __shfl_xor(lmin, off));
    }
    if ((tid & 63) == 0) {
        atomicMax(&maxenc[t], enc(lmax));
        atomicMin(&minenc[t], enc(lmin));
    }
}

// ---------------------------------------------------------------------------
// Kernel 3: combine, misfit transform, damping, final sum
// ---------------------------------------------------------------------------
__global__ __launch_bounds__(512) void finalize_kernel(
    const float* __restrict__ b,
    const unsigned* __restrict__ maxenc, const unsigned* __restrict__ minenc,
    const float* __restrict__ e00vals, float* __restrict__ out) {

    int tid = threadIdx.x;
    float acc = 0.0f;

    if (tid < NOBS) {
        float mx = dec(maxenc[tid]);
        float mn = dec(minenc[tid]);
        float rng  = mx - mn;
        float e00  = e00vals[tid] / rng;
        float term = exp2f(LOG2_0P1 * fabsf(e00)) - 1.0f;  // 0.1^|e00| - 1
        acc = fabsf(term) * (1.0f / (float)NOBS);
    }
    if (tid < NL) {
        float bi = b[tid];
        float lb;
        if (tid == 0)            lb = bi - b[1];
        else if (tid == NL - 1)  lb = bi - b[NL - 2];
        else                     lb = 2.0f * bi - b[tid - 1] - b[tid + 1];
        acc += fabsf(lb * (1.0f / (float)NL));   // DAMP = 1.0
    }

    __shared__ float s[512];
    s[tid] = acc;
    __syncthreads();
    for (int st = 256; st > 0; st >>= 1) {
        if (tid < st) s[tid] += s[tid + st];
        __syncthreads();
    }
    if (tid == 0) out[0] = s[0];
}

// ---------------------------------------------------------------------------
extern "C" void kernel_launch(void* const* d_in, const int* in_sizes, int n_in,
                              void* d_out, int out_size, void* d_ws, size_t ws_size,
                              hipStream_t stream) {
    const float* vlist = (const float*)d_in[0];
    const float* tlist = (const float*)d_in[1];
    const float* d     = (const float*)d_in[2];
    const float* b     = (const float*)d_in[3];
    const float* Clist = (const float*)d_in[4];
    float* out = (float*)d_out;

    float*    ws      = (float*)d_ws;
    float*    a_arr   = ws;                       // 64
    float*    rho_arr = ws + 64;                  // 64
    float*    e00v    = ws + 128;                 // 400
    unsigned* maxenc  = (unsigned*)(ws + 528);    // 400
    unsigned* minenc  = (unsigned*)(ws + 928);    // 400   (total ~5.3 KB)

    prep_kernel<<<1, 256, 0, stream>>>(b, a_arr, rho_arr, maxenc, minenc);
    det_kernel<<<dim3(NCHUNK, NOBS), 128, 0, stream>>>(vlist, tlist, d, b, Clist,
                                                       a_arr, rho_arr, maxenc, minenc, e00v);
    finalize_kernel<<<1, 512, 0, stream>>>(b, maxenc, minenc, e00v, out);
}

// Round 4
// 420.952 us; speedup vs baseline: 1.6716x; 1.6716x over previous
//
#include <hip/hip_runtime.h>
#include <math.h>
#include <float.h>

#define NL     64
#define NOBS   400
#define NC     3000
#define CHUNK  128
#define NCHUNK 24            // 24*128 = 3072 >= 3000 grid pts + 1 sentinel
#define TWO_PI_F   6.2831853071795864769f
#define INV_2PI_F  0.15915494309189535f
#define LOG2E_F    1.4426950408889634f
#define LOG2_0P1  -3.3219280948873623f

__device__ __forceinline__ float hsin(float x)  { return __builtin_amdgcn_sinf(x); }   // arg pre-scaled by 1/2pi
__device__ __forceinline__ float hcos(float x)  { return __builtin_amdgcn_cosf(x); }
__device__ __forceinline__ float hexp2(float x) { return __builtin_amdgcn_exp2f(x); }
__device__ __forceinline__ float hrcp(float x)  { return __builtin_amdgcn_rcpf(x); }
__device__ __forceinline__ float hsqrt(float x) { return __builtin_amdgcn_sqrtf(x); }

// monotone float <-> uint encoding for atomic max/min
__device__ __forceinline__ unsigned enc(float f) {
    unsigned u = __float_as_uint(f);
    return (u & 0x80000000u) ? ~u : (u | 0x80000000u);
}
__device__ __forceinline__ float dec(unsigned k) {
    unsigned u = (k & 0x80000000u) ? (k & 0x7fffffffu) : ~k;
    return __uint_as_float(u);
}

// ---------------------------------------------------------------------------
// Kernel 1: Brocher b->(a,rho) + init atomic slots
// ---------------------------------------------------------------------------
__global__ void prep_kernel(const float* __restrict__ b, float* __restrict__ a_out,
                            float* __restrict__ rho_out,
                            unsigned* __restrict__ maxenc, unsigned* __restrict__ minenc) {
    int i = threadIdx.x;   // 256 threads
    if (i < NL) {
        float bb = b[i];
        float b2 = bb * bb, b3 = b2 * bb, b4 = b3 * bb;
        float a = 0.9409f + 2.0947f * bb - 0.8206f * b2 + 0.2683f * b3 - 0.0251f * b4;
        float a2 = a * a, a3 = a2 * a, a4 = a3 * a, a5 = a4 * a;
        float rho = 1.6612f * a - 0.4721f * a2 + 0.0671f * a3 - 0.0043f * a4 + 0.000106f * a5;
        a_out[i] = a;
        rho_out[i] = rho;
    }
    for (int j = i; j < NOBS; j += 256) {
        maxenc[j] = 0u;            // below enc of any finite float
        minenc[j] = 0xFFFFFFFFu;   // above enc of any finite float
    }
}

// ---------------------------------------------------------------------------
// One Dunkin layer step. P points to this layer's 16-float LDS record:
// [xka, xkb, gammk, dm, dms(dm/2pi), dme(-2*log2e*dm), rm, irm, rho2, irho2]
// ---------------------------------------------------------------------------
template <bool NORM>
__device__ __forceinline__ void layer_step(
    float& e0, float& e1, float& e2, float& e3, float& e4,
    const float* __restrict__ P,
    float wvno, float wvno2, float wvno4, float t2, float w2x2) {

    float xka = P[0], xkb = P[1], gammk = P[2], dm = P[3];
    float dms = P[4], dme = P[5], rm = P[6], irm = P[7];
    float rho2 = P[8], irho2 = P[9];

    float ra = hsqrt((wvno + xka) * fabsf(wvno - xka));
    float rb = hsqrt((wvno + xkb) * fabsf(wvno - xkb));
    float gam = gammk * wvno2;
    float p = ra * dm, q = rb * dm;

    float ra_s = (ra > 0.0f) ? ra : 1.0f;
    float rb_s = (rb > 0.0f) ? rb : 1.0f;
    float rp  = hrcp(ra_s * rb_s);
    float ira = rb_s * rp;
    float irb = ra_s * rp;

    float sinp = hsin(ra * dms);
    float cospt = hcos(ra * dms);
    float facp = hexp2(ra * dme);
    float sinq = hsin(rb * dms);
    float cosqt = hcos(rb * dms);
    float facq = hexp2(rb * dme);

    bool ltp = wvno < xka;
    bool lts = wvno < xkb;
    float sinp_e = 0.5f - 0.5f * facp;
    float sinq_e = 0.5f - 0.5f * facq;
    float pex = ltp ? 0.0f : p;
    float sex = lts ? 0.0f : q;
    float cosp = ltp ? cospt : (0.5f + 0.5f * facp);
    float cosq = lts ? cosqt : (0.5f + 0.5f * facq);
    float w = (ltp ? sinp : sinp_e) * ira;
    float x = ra * (ltp ? -sinp : sinp_e);
    float y = (lts ? sinq : sinq_e) * irb;
    float z = rb * (lts ? -sinq : sinq_e);
    float a0 = hexp2(-LOG2E_F * (pex + sex));

    float cpcq = cosp * cosq;
    float cpy = cosp * y, cpz = cosp * z;
    float cqw = cosq * w, cqx = cosq * x;
    float xy = x * y, xz = x * z, wy = w * y, wz = w * z;

    float gamm1 = gam - 1.0f;
    float twgm1 = gam + gamm1;
    float gmgmk = gam * gammk;
    float gmgm1 = gam * gamm1;
    float gm1sq = gamm1 * gamm1;
    float a0pq  = a0 - cpcq;

    float c00 = cpcq - 2.0f * gmgm1 * a0pq - gmgmk * xz - wvno2 * gm1sq * wy;
    float c01 = (wvno2 * cpy - cqx) * irm;
    float c02 = -(twgm1 * a0pq + gammk * xz + wvno2 * gamm1 * wy) * irm;
    float c03 = (cpz - wvno2 * cqw) * irm;
    float c04 = -(w2x2 * a0pq + xz + wvno4 * wy) * irho2;
    float c10 = (gmgmk * cpz - gm1sq * cqw) * rm;
    float c12 = gammk * cpz - gamm1 * cqw;
    float c30 = (gm1sq * cpy - gmgmk * cqx) * rm;
    float c32 = gamm1 * cpy - gammk * cqx;
    float q1  = gmgmk * gm1sq;
    float c40 = -(2.0f * q1 * a0pq + gmgmk * gmgmk * xz + gm1sq * gm1sq * wy) * rho2;
    float c42 = -(gmgm1 * twgm1 * a0pq + gmgmk * gammk * xz + gamm1 * gm1sq * wy) * rm;
    float c22 = a0 + 2.0f * (cpcq - c00);

    float e2t = e2 * t2;   // row 2 of ca = t2 * {c42, c32, -, c12, c02}

    float ee0 = e0 * c00 + e1 * c10 + e2t * c42 + e3 * c30 + e4 * c40;
    float ee1 = e0 * c01 + e1 * cpcq + e2t * c32 - e3 * xy + e4 * c30;
    float ee2 = e0 * c02 + e1 * c12 + e2 * c22 + e3 * c32 + e4 * c42;
    float ee3 = e0 * c03 - e1 * wz + e2t * c12 + e3 * cpcq + e4 * c10;
    float ee4 = e0 * c04 + e1 * c03 + e2t * c02 + e3 * c01 + e4 * c00;

    if (NORM) {
        float nrm = fmaxf(fmaxf(fmaxf(fabsf(ee0), fabsf(ee1)),
                                fmaxf(fabsf(ee2), fabsf(ee3))), fabsf(ee4));
        nrm = fmaxf(nrm, 1e-30f);
        float inv = hrcp(nrm);
        e0 = ee0 * inv; e1 = ee1 * inv; e2 = ee2 * inv; e3 = ee3 * inv; e4 = ee4 * inv;
    } else {
        e0 = ee0; e1 = ee1; e2 = ee2; e3 = ee3; e4 = ee4;
    }
}

__device__ float det_eval(float cvel, float omega, const float* __restrict__ Lf) {
    float wvno  = omega * hrcp(cvel);
    float wvno2 = wvno * wvno;
    float wvno4 = wvno2 * wvno2;
    float t2    = -2.0f * wvno2;
    float w2x2  = 2.0f * wvno2;

    // halfspace (layer NL-1)
    const float* P = &Lf[(NL - 1) * 16];
    float xka = P[0], xkb = P[1], gammk = P[2], r = P[6];
    float ra = hsqrt((wvno + xka) * fabsf(wvno - xka));
    float rb = hsqrt((wvno + xkb) * fabsf(wvno - xkb));
    float gam = gammk * wvno2;
    float gamm1 = gam - 1.0f;
    float rarb = ra * rb;

    float e0 = r * r * (gamm1 * gamm1 - gam * gammk * rarb);
    float e1 = -r * ra;
    float e2 = r * (gamm1 - gammk * rarb);
    float e3 = r * rb;
    float e4 = wvno2 - rarb;

    // 63 layers: pairs (62,61)...(2,1) with norm on 2nd of each, then 0 (norm).
    #pragma unroll 1
    for (int m = NL - 2; m >= 2; m -= 2) {
        layer_step<false>(e0, e1, e2, e3, e4, &Lf[m * 16], wvno, wvno2, wvno4, t2, w2x2);
        layer_step<true >(e0, e1, e2, e3, e4, &Lf[(m - 1) * 16], wvno, wvno2, wvno4, t2, w2x2);
    }
    layer_step<true>(e0, e1, e2, e3, e4, &Lf[0], wvno, wvno2, wvno4, t2, w2x2);
    return e0;
}

// ---------------------------------------------------------------------------
// Kernel 2: one det per thread; wave-reduce max/min; atomics per wave.
// grid = (NCHUNK, NOBS), block = 128. idx==NC is the (vlist[t],tlist[t]) sentinel.
// ---------------------------------------------------------------------------
__global__ __launch_bounds__(128, 2) void det_kernel(
    const float* __restrict__ vlist, const float* __restrict__ tlist,
    const float* __restrict__ d, const float* __restrict__ b,
    const float* __restrict__ Clist,
    const float* __restrict__ a_arr, const float* __restrict__ rho_arr,
    unsigned* __restrict__ maxenc, unsigned* __restrict__ minenc,
    float* __restrict__ e00vals) {

    __shared__ float Lf[NL * 16];

    int t     = blockIdx.y;
    int chunk = blockIdx.x;
    int tid   = threadIdx.x;

    float omega = fmaxf(TWO_PI_F / tlist[t], 0.0001f);

    if (tid < NL) {
        float am = a_arr[tid];
        float bm = b[tid];
        float rm = rho_arr[tid];
        float dm = d[tid];
        float* P = &Lf[tid * 16];
        P[0] = omega / am;
        P[1] = omega / bm;
        float tt = bm / omega;
        P[2] = 2.0f * tt * tt;
        P[3] = dm;
        P[4] = dm * INV_2PI_F;
        P[5] = -2.0f * LOG2E_F * dm;
        P[6] = rm;
        P[7] = 1.0f / rm;
        P[8] = rm * rm;
        P[9] = 1.0f / (rm * rm);
    }
    __syncthreads();

    int idx = chunk * CHUNK + tid;
    float lmax = -FLT_MAX, lmin = FLT_MAX;

    if (idx <= NC) {
        bool grid_pt = idx < NC;
        float cvel = grid_pt ? Clist[idx] : vlist[t];
        float det  = det_eval(cvel, omega, Lf);
        if (grid_pt) {
            lmax = det;
            lmin = det;
        } else {
            e00vals[t] = det;
        }
    }

    // wave-level butterfly reduce (64 lanes)
    #pragma unroll
    for (int off = 32; off >= 1; off >>= 1) {
        lmax = fmaxf(lmax, __shfl_xor(lmax, off));
        lmin = fminf(lmin, __shfl_xor(lmin, off));
    }
    if ((tid & 63) == 0) {
        atomicMax(&maxenc[t], enc(lmax));
        atomicMin(&minenc[t], enc(lmin));
    }
}

// ---------------------------------------------------------------------------
// Kernel 3: combine, misfit transform, damping, final sum
// ---------------------------------------------------------------------------
__global__ __launch_bounds__(512) void finalize_kernel(
    const float* __restrict__ b,
    const unsigned* __restrict__ maxenc, const unsigned* __restrict__ minenc,
    const float* __restrict__ e00vals, float* __restrict__ out) {

    int tid = threadIdx.x;
    float acc = 0.0f;

    if (tid < NOBS) {
        float mx = dec(maxenc[tid]);
        float mn = dec(minenc[tid]);
        float rng  = mx - mn;
        float e00  = e00vals[tid] / rng;
        float term = exp2f(LOG2_0P1 * fabsf(e00)) - 1.0f;  // 0.1^|e00| - 1
        acc = fabsf(term) * (1.0f / (float)NOBS);
    }
    if (tid < NL) {
        float bi = b[tid];
        float lb;
        if (tid == 0)            lb = bi - b[1];
        else if (tid == NL - 1)  lb = bi - b[NL - 2];
        else                     lb = 2.0f * bi - b[tid - 1] - b[tid + 1];
        acc += fabsf(lb * (1.0f / (float)NL));   // DAMP = 1.0
    }

    __shared__ float s[512];
    s[tid] = acc;
    __syncthreads();
    for (int st = 256; st > 0; st >>= 1) {
        if (tid < st) s[tid] += s[tid + st];
        __syncthreads();
    }
    if (tid == 0) out[0] = s[0];
}

// ---------------------------------------------------------------------------
extern "C" void kernel_launch(void* const* d_in, const int* in_sizes, int n_in,
                              void* d_out, int out_size, void* d_ws, size_t ws_size,
                              hipStream_t stream) {
    const float* vlist = (const float*)d_in[0];
    const float* tlist = (const float*)d_in[1];
    const float* d     = (const float*)d_in[2];
    const float* b     = (const float*)d_in[3];
    const float* Clist = (const float*)d_in[4];
    float* out = (float*)d_out;

    float*    ws      = (float*)d_ws;
    float*    a_arr   = ws;                       // 64
    float*    rho_arr = ws + 64;                  // 64
    float*    e00v    = ws + 128;                 // 400
    unsigned* maxenc  = (unsigned*)(ws + 528);    // 400
    unsigned* minenc  = (unsigned*)(ws + 928);    // 400   (total ~5.3 KB)

    prep_kernel<<<1, 256, 0, stream>>>(b, a_arr, rho_arr, maxenc, minenc);
    det_kernel<<<dim3(NCHUNK, NOBS), 128, 0, stream>>>(vlist, tlist, d, b, Clist,
                                                       a_arr, rho_arr, maxenc, minenc, e00v);
    finalize_kernel<<<1, 512, 0, stream>>>(b, maxenc, minenc, e00v, out);
}

// Round 5
// 320.126 us; speedup vs baseline: 2.1980x; 1.3150x over previous
//
#include <hip/hip_runtime.h>
#include <math.h>
#include <float.h>

#define NL     64
#define NOBS   400
#define NC     3000
#define CHUNK  128
#define NCHUNK 24            // 24*128 = 3072 >= 3000 grid pts + 1 sentinel
#define TWO_PI_F   6.2831853071795864769f
#define INV_2PI_F  0.15915494309189535f
#define LOG2E_F    1.4426950408889634f
#define LOG2_0P1  -3.3219280948873623f

__device__ __forceinline__ float hsin(float x)  { return __builtin_amdgcn_sinf(x); }   // arg in revolutions
__device__ __forceinline__ float hcos(float x)  { return __builtin_amdgcn_cosf(x); }
__device__ __forceinline__ float hexp2(float x) { return __builtin_amdgcn_exp2f(x); }
__device__ __forceinline__ float hrcp(float x)  { return __builtin_amdgcn_rcpf(x); }
__device__ __forceinline__ float hsqrt(float x) { return __builtin_amdgcn_sqrtf(x); }

// monotone float <-> uint encoding for atomic max/min
__device__ __forceinline__ unsigned enc(float f) {
    unsigned u = __float_as_uint(f);
    return (u & 0x80000000u) ? ~u : (u | 0x80000000u);
}
__device__ __forceinline__ float dec(unsigned k) {
    unsigned u = (k & 0x80000000u) ? (k & 0x7fffffffu) : ~k;
    return __uint_as_float(u);
}

// ---------------------------------------------------------------------------
// Kernel 1: Brocher b->(a,rho) + init atomic slots
// ---------------------------------------------------------------------------
__global__ void prep_kernel(const float* __restrict__ b, float* __restrict__ a_out,
                            float* __restrict__ rho_out,
                            unsigned* __restrict__ maxenc, unsigned* __restrict__ minenc) {
    int i = threadIdx.x;   // 256 threads
    if (i < NL) {
        float bb = b[i];
        float b2 = bb * bb, b3 = b2 * bb, b4 = b3 * bb;
        float a = 0.9409f + 2.0947f * bb - 0.8206f * b2 + 0.2683f * b3 - 0.0251f * b4;
        float a2 = a * a, a3 = a2 * a, a4 = a3 * a, a5 = a4 * a;
        float rho = 1.6612f * a - 0.4721f * a2 + 0.0671f * a3 - 0.0043f * a4 + 0.000106f * a5;
        a_out[i] = a;
        rho_out[i] = rho;
    }
    for (int j = i; j < NOBS; j += 256) {
        maxenc[j] = 0u;            // below enc of any finite float
        minenc[j] = 0xFFFFFFFFu;   // above enc of any finite float
    }
}

// ---------------------------------------------------------------------------
// Layer record (8 floats in LDS):
// [0]=xka2  [1]=xkb2  [2]=gammk  [3]=dmsin(dm/2pi)  [4]=dmexp(-2*log2e*dm)
// [5]=rho_ratio(rho[m]/rho[m+1])  [6]=ratio^2  [7]=pad
// Tracks f = e * diag(1, rho, rho, rho, rho^2): all rm factors fall out of C'.
// ---------------------------------------------------------------------------
template <bool NORM>
__device__ __forceinline__ void layer_step(
    float& f0, float& f1, float& f2, float& f3, float& f4,
    const float* __restrict__ P, float wvno2, float t2) {

    float xka2 = P[0], xkb2 = P[1], gammk = P[2];
    float dmsin = P[3], dmexp = P[4];
    float rr = P[5], rr2 = P[6];

    // density-ratio prescale (D = S_{m+1}^{-1} S_m)
    f1 *= rr; f2 *= rr; f3 *= rr; f4 *= rr2;

    float ra2 = wvno2 - xka2;
    float rb2 = wvno2 - xkb2;
    float ra = hsqrt(fabsf(ra2));
    float rb = hsqrt(fabsf(rb2));
    float gam = gammk * wvno2;

    bool ltp = ra2 < 0.0f;    // propagating P
    bool lts = rb2 < 0.0f;    // propagating S

    float ra_s = fmaxf(ra, 1e-18f);
    float rb_s = fmaxf(rb, 1e-18f);
    float rp  = hrcp(ra_s * rb_s);
    float ira = rb_s * rp;
    float irb = ra_s * rp;

    // ---- P side ----
    float cosp, w, x, fp;
    if (__all(ltp)) {
        float s = hsin(ra * dmsin);
        cosp = hcos(ra * dmsin);
        w = s * ira;
        x = -ra * s;
        fp = 1.0f;
    } else if (__all(!ltp)) {
        float f = hexp2(ra * dmexp);
        float se = 0.5f - 0.5f * f;
        cosp = 0.5f + 0.5f * f;
        w = se * ira;
        x = ra * se;
        fp = f;
    } else {
        float s = hsin(ra * dmsin);
        float c = hcos(ra * dmsin);
        float f = hexp2(ra * dmexp);
        float se = 0.5f - 0.5f * f;
        cosp = ltp ? c : (0.5f + 0.5f * f);
        float wn = ltp ? s : se;
        float xn = ltp ? -s : se;
        w = wn * ira;
        x = ra * xn;
        fp = ltp ? 1.0f : f;
    }

    // ---- S side ----
    float cosq, y, z, fq;
    if (__all(lts)) {
        float s = hsin(rb * dmsin);
        cosq = hcos(rb * dmsin);
        y = s * irb;
        z = -rb * s;
        fq = 1.0f;
    } else if (__all(!lts)) {
        float f = hexp2(rb * dmexp);
        float se = 0.5f - 0.5f * f;
        cosq = 0.5f + 0.5f * f;
        y = se * irb;
        z = rb * se;
        fq = f;
    } else {
        float s = hsin(rb * dmsin);
        float c = hcos(rb * dmsin);
        float f = hexp2(rb * dmexp);
        float se = 0.5f - 0.5f * f;
        cosq = lts ? c : (0.5f + 0.5f * f);
        float yn = lts ? s : se;
        float zn = lts ? -s : se;
        y = yn * irb;
        z = rb * zn;
        fq = lts ? 1.0f : f;
    }

    // a0 = exp(-(pex+sex)) == sqrt(fp*fq)   (fp = exp(-2p) iff evanescent, else 1)
    float a0 = hsqrt(fp * fq);

    float cpcq = cosp * cosq;
    float cpy = cosp * y, cpz = cosp * z;
    float cqw = cosq * w, cqx = cosq * x;
    float xy = x * y, xz = x * z, wy = w * y, wz = w * z;

    float gamm1 = gam - 1.0f;
    float twgm1 = gam + gamm1;
    float gmgmk = gam * gammk;
    float gmgm1 = gam * gamm1;
    float gm1sq = gamm1 * gamm1;

    float a0pq  = a0 - cpcq;
    float a0pq2 = a0pq + a0pq;
    float nwy   = wvno2 * wy;
    float gw    = gm1sq * wy;

    // rm-free C' entries (nc* are the negated forms)
    float c00  = cpcq - gmgm1 * a0pq2 - gmgmk * xz - gm1sq * nwy;
    float c01  = wvno2 * cpy - cqx;
    float nc02 = twgm1 * a0pq + gammk * xz + gamm1 * nwy;
    float c03  = cpz - wvno2 * cqw;
    float nc04 = wvno2 * a0pq2 + xz + wvno2 * nwy;
    float c10  = gmgmk * cpz - gm1sq * cqw;
    float c12  = gammk * cpz - gamm1 * cqw;
    float c30  = gm1sq * cpy - gmgmk * cqx;
    float c32  = gamm1 * cpy - gammk * cqx;
    float t40  = gm1sq * a0pq2 + gmgmk * xz;
    float nc40 = gmgmk * t40 + gm1sq * gw;
    float th   = gmgm1 * twgm1;
    float nc42 = th * a0pq + (gmgmk * gammk) * xz + gamm1 * gw;
    float c22  = a0 + 2.0f * (cpcq - c00);

    float e2t = f2 * t2;   // row 2 of C' = t2 * {-nc42, c32, c22/t2.., c12, -nc02}

    float ee0 =  f0 * c00  + f1 * c10  - e2t * nc42 + f3 * c30  - f4 * nc40;
    float ee1 =  f0 * c01  + f1 * cpcq + e2t * c32  - f3 * xy   + f4 * c30;
    float ee2 = -f0 * nc02 + f1 * c12  + f2 * c22   + f3 * c32  - f4 * nc42;
    float ee3 =  f0 * c03  - f1 * wz   + e2t * c12  + f3 * cpcq + f4 * c10;
    float ee4 = -f0 * nc04 + f1 * c03  - e2t * nc02 + f3 * c01  + f4 * c00;

    if (NORM) {
        float nrm = fmaxf(fmaxf(fmaxf(fabsf(ee0), fabsf(ee1)),
                                fmaxf(fabsf(ee2), fabsf(ee3))), fabsf(ee4));
        nrm = fmaxf(nrm, 1e-30f);
        // exact power-of-2 inverse of nrm's exponent (no rcp, no rounding)
        unsigned nb = __float_as_uint(nrm) & 0x7f800000u;
        float inv = __uint_as_float(0x7f000000u - nb);
        f0 = ee0 * inv; f1 = ee1 * inv; f2 = ee2 * inv; f3 = ee3 * inv; f4 = ee4 * inv;
    } else {
        f0 = ee0; f1 = ee1; f2 = ee2; f3 = ee3; f4 = ee4;
    }
}

__device__ float det_eval(float cvel, float omega, const float* __restrict__ Lf, float ir0) {
    float wvno  = omega * hrcp(cvel);
    float wvno2 = wvno * wvno;
    float t2    = -2.0f * wvno2;

    // halfspace (layer NL-1), rho factors dropped (global scale is irrelevant)
    const float* P = &Lf[(NL - 1) * 8];
    float ra = hsqrt(fabsf(wvno2 - P[0]));
    float rb = hsqrt(fabsf(wvno2 - P[1]));
    float gammk = P[2];
    float gam = gammk * wvno2;
    float gamm1 = gam - 1.0f;
    float rarb = ra * rb;

    float f0 = gamm1 * gamm1 - gam * gammk * rarb;
    float f1 = -ra;
    float f2 = gamm1 - gammk * rarb;
    float f3 = rb;
    float f4 = wvno2 - rarb;

    // 63 layers: 20 triplets (62..3) with norm on 3rd, then 2,1,0 plain.
    #pragma unroll 1
    for (int m = NL - 2; m >= 5; m -= 3) {
        layer_step<false>(f0, f1, f2, f3, f4, &Lf[m * 8], wvno2, t2);
        layer_step<false>(f0, f1, f2, f3, f4, &Lf[(m - 1) * 8], wvno2, t2);
        layer_step<true >(f0, f1, f2, f3, f4, &Lf[(m - 2) * 8], wvno2, t2);
    }
    layer_step<false>(f0, f1, f2, f3, f4, &Lf[2 * 8], wvno2, t2);
    layer_step<false>(f0, f1, f2, f3, f4, &Lf[1 * 8], wvno2, t2);
    layer_step<false>(f0, f1, f2, f3, f4, &Lf[0 * 8], wvno2, t2);

    // unscale to e-space (S_0 = diag(1, r0, r0, r0, r0^2)) and final max-norm
    float m123 = fmaxf(fmaxf(fabsf(f1), fabsf(f2)), fabsf(f3)) * ir0;
    float nrm = fmaxf(fabsf(f0), fmaxf(m123, fabsf(f4) * (ir0 * ir0)));
    return f0 * hrcp(nrm);
}

// ---------------------------------------------------------------------------
// Kernel 2: one det per thread; wave-reduce max/min; atomics per wave.
// grid = (NCHUNK, NOBS), block = 128. idx==NC is the (vlist[t],tlist[t]) sentinel.
// ---------------------------------------------------------------------------
__global__ __launch_bounds__(128, 2) void det_kernel(
    const float* __restrict__ vlist, const float* __restrict__ tlist,
    const float* __restrict__ d, const float* __restrict__ b,
    const float* __restrict__ Clist,
    const float* __restrict__ a_arr, const float* __restrict__ rho_arr,
    unsigned* __restrict__ maxenc, unsigned* __restrict__ minenc,
    float* __restrict__ e00vals) {

    __shared__ float Lf[NL * 8];
    __shared__ float s_ir0;

    int t     = blockIdx.y;
    int chunk = blockIdx.x;
    int tid   = threadIdx.x;

    float omega = fmaxf(TWO_PI_F / tlist[t], 0.0001f);

    if (tid < NL) {
        float am = a_arr[tid];
        float bm = b[tid];
        float dm = d[tid];
        float* P = &Lf[tid * 8];
        float ta = omega / am;
        float tb = omega / bm;
        P[0] = ta * ta;
        P[1] = tb * tb;
        float tt = bm / omega;
        P[2] = 2.0f * tt * tt;
        P[3] = dm * INV_2PI_F;
        P[4] = -2.0f * LOG2E_F * dm;
        float rr = (tid < NL - 1) ? (rho_arr[tid] / rho_arr[tid + 1]) : 1.0f;
        P[5] = rr;
        P[6] = rr * rr;
        P[7] = 0.0f;
        if (tid == 0) s_ir0 = 1.0f / rho_arr[0];
    }
    __syncthreads();

    int idx = chunk * CHUNK + tid;
    float lmax = -FLT_MAX, lmin = FLT_MAX;

    if (idx <= NC) {
        bool grid_pt = idx < NC;
        float cvel = grid_pt ? Clist[idx] : vlist[t];
        float det  = det_eval(cvel, omega, Lf, s_ir0);
        if (grid_pt) {
            lmax = det;
            lmin = det;
        } else {
            e00vals[t] = det;
        }
    }

    // wave-level butterfly reduce (64 lanes)
    #pragma unroll
    for (int off = 32; off >= 1; off >>= 1) {
        lmax = fmaxf(lmax, __shfl_xor(lmax, off));
        lmin = fminf(lmin, __shfl_xor(lmin, off));
    }
    if ((tid & 63) == 0) {
        atomicMax(&maxenc[t], enc(lmax));
        atomicMin(&minenc[t], enc(lmin));
    }
}

// ---------------------------------------------------------------------------
// Kernel 3: combine, misfit transform, damping, final sum
// ---------------------------------------------------------------------------
__global__ __launch_bounds__(512) void finalize_kernel(
    const float* __restrict__ b,
    const unsigned* __restrict__ maxenc, const unsigned* __restrict__ minenc,
    const float* __restrict__ e00vals, float* __restrict__ out) {

    int tid = threadIdx.x;
    float acc = 0.0f;

    if (tid < NOBS) {
        float mx = dec(maxenc[tid]);
        float mn = dec(minenc[tid]);
        float rng  = mx - mn;
        float e00  = e00vals[tid] / rng;
        float term = exp2f(LOG2_0P1 * fabsf(e00)) - 1.0f;  // 0.1^|e00| - 1
        acc = fabsf(term) * (1.0f / (float)NOBS);
    }
    if (tid < NL) {
        float bi = b[tid];
        float lb;
        if (tid == 0)            lb = bi - b[1];
        else if (tid == NL - 1)  lb = bi - b[NL - 2];
        else                     lb = 2.0f * bi - b[tid - 1] - b[tid + 1];
        acc += fabsf(lb * (1.0f / (float)NL));   // DAMP = 1.0
    }

    __shared__ float s[512];
    s[tid] = acc;
    __syncthreads();
    for (int st = 256; st > 0; st >>= 1) {
        if (tid < st) s[tid] += s[tid + st];
        __syncthreads();
    }
    if (tid == 0) out[0] = s[0];
}

// ---------------------------------------------------------------------------
extern "C" void kernel_launch(void* const* d_in, const int* in_sizes, int n_in,
                              void* d_out, int out_size, void* d_ws, size_t ws_size,
                              hipStream_t stream) {
    const float* vlist = (const float*)d_in[0];
    const float* tlist = (const float*)d_in[1];
    const float* d     = (const float*)d_in[2];
    const float* b     = (const float*)d_in[3];
    const float* Clist = (const float*)d_in[4];
    float* out = (float*)d_out;

    float*    ws      = (float*)d_ws;
    float*    a_arr   = ws;                       // 64
    float*    rho_arr = ws + 64;                  // 64
    float*    e00v    = ws + 128;                 // 400
    unsigned* maxenc  = (unsigned*)(ws + 528);    // 400
    unsigned* minenc  = (unsigned*)(ws + 928);    // 400   (total ~5.3 KB)

    prep_kernel<<<1, 256, 0, stream>>>(b, a_arr, rho_arr, maxenc, minenc);
    det_kernel<<<dim3(NCHUNK, NOBS), 128, 0, stream>>>(vlist, tlist, d, b, Clist,
                                                       a_arr, rho_arr, maxenc, minenc, e00v);
    finalize_kernel<<<1, 512, 0, stream>>>(b, maxenc, minenc, e00v, out);
}

// Round 7
// 196.610 us; speedup vs baseline: 3.5789x; 1.6282x over previous
//
#include <hip/hip_runtime.h>
#include <math.h>
#include <float.h>

#define NL      64
#define NOBS    400
#define NC      3000
#define HALF_NC 1500
#define CHUNK   128
#define NCHUNK  12           // 12*128 = 1536 >= 1500 pairs + 1 sentinel
#define TWO_PI_F   6.2831853071795864769f
#define INV_2PI_F  0.15915494309189535f
#define LOG2E_F    1.4426950408889634f
#define LOG2_0P1  -3.3219280948873623f

typedef float fx2 __attribute__((ext_vector_type(2)));

__device__ __forceinline__ float hsin(float x)  { return __builtin_amdgcn_sinf(x); }
__device__ __forceinline__ float hcos(float x)  { return __builtin_amdgcn_cosf(x); }
__device__ __forceinline__ float hexp2(float x) { return __builtin_amdgcn_exp2f(x); }
__device__ __forceinline__ float hrcp(float x)  { return __builtin_amdgcn_rcpf(x); }
__device__ __forceinline__ float hsqrt(float x) { return __builtin_amdgcn_sqrtf(x); }

__device__ __forceinline__ fx2 v_sqrt(fx2 v) { fx2 r; r.x = hsqrt(v.x); r.y = hsqrt(v.y); return r; }
__device__ __forceinline__ fx2 v_rcp (fx2 v) { fx2 r; r.x = hrcp(v.x);  r.y = hrcp(v.y);  return r; }
__device__ __forceinline__ fx2 v_sin (fx2 v) { fx2 r; r.x = hsin(v.x);  r.y = hsin(v.y);  return r; }
__device__ __forceinline__ fx2 v_cos (fx2 v) { fx2 r; r.x = hcos(v.x);  r.y = hcos(v.y);  return r; }
__device__ __forceinline__ fx2 v_exp2(fx2 v) { fx2 r; r.x = hexp2(v.x); r.y = hexp2(v.y); return r; }
__device__ __forceinline__ fx2 v_abs (fx2 v) { fx2 r; r.x = fabsf(v.x); r.y = fabsf(v.y); return r; }
__device__ __forceinline__ fx2 v_max (fx2 a, fx2 b) { fx2 r; r.x = fmaxf(a.x, b.x); r.y = fmaxf(a.y, b.y); return r; }

// monotone float <-> uint encoding for atomic max/min
__device__ __forceinline__ unsigned enc(float f) {
    unsigned u = __float_as_uint(f);
    return (u & 0x80000000u) ? ~u : (u | 0x80000000u);
}
__device__ __forceinline__ float dec(unsigned k) {
    unsigned u = (k & 0x80000000u) ? (k & 0x7fffffffu) : ~k;
    return __uint_as_float(u);
}

// ---------------------------------------------------------------------------
// Kernel 1: Brocher b->(a,rho) + init atomic slots
// ---------------------------------------------------------------------------
__global__ void prep_kernel(const float* __restrict__ b, float* __restrict__ a_out,
                            float* __restrict__ rho_out,
                            unsigned* __restrict__ maxenc, unsigned* __restrict__ minenc) {
    int i = threadIdx.x;   // 256 threads
    if (i < NL) {
        float bb = b[i];
        float b2 = bb * bb, b3 = b2 * bb, b4 = b3 * bb;
        float a = 0.9409f + 2.0947f * bb - 0.8206f * b2 + 0.2683f * b3 - 0.0251f * b4;
        float a2 = a * a, a3 = a2 * a, a4 = a3 * a, a5 = a4 * a;
        float rho = 1.6612f * a - 0.4721f * a2 + 0.0671f * a3 - 0.0043f * a4 + 0.000106f * a5;
        a_out[i] = a;
        rho_out[i] = rho;
    }
    for (int j = i; j < NOBS; j += 256) {
        maxenc[j] = 0u;            // below enc of any finite float
        minenc[j] = 0xFFFFFFFFu;   // above enc of any finite float
    }
}

// ---------------------------------------------------------------------------
// Layer record (8 floats in LDS):
// [0]=xka2 [1]=xkb2 [2]=gammk [3]=dmsin(dm/2pi) [4]=dmexp(-2*log2e*dm)
// [5]=rho_ratio [6]=ratio^2 [7]=pad
// Tracks f = e * diag(1, rho, rho, rho, rho^2); 2 dets packed per lane (fx2).
// ---------------------------------------------------------------------------

struct SideVals { float cosv, wv, xv, fv; };

// mixed propagating/evanescent side, one component (returns by value)
__device__ __forceinline__ SideVals side_mixed(float ra, bool lt, float dmsin,
                                               float dmexp, float ir) {
    float s = hsin(ra * dmsin);
    float c = hcos(ra * dmsin);
    float f = hexp2(ra * dmexp);
    float se = 0.5f - 0.5f * f;
    SideVals r;
    r.cosv = lt ? c : (0.5f + 0.5f * f);
    r.wv = (lt ? s : se) * ir;
    r.xv = ra * (lt ? -s : se);
    r.fv = lt ? 1.0f : f;
    return r;
}

template <bool NORM>
__device__ __forceinline__ void layer_step(
    fx2& f0, fx2& f1, fx2& f2, fx2& f3, fx2& f4,
    const float* __restrict__ P, fx2 wvno2, fx2 t2) {

    float xka2 = P[0], xkb2 = P[1], gammk = P[2];
    float dmsin = P[3], dmexp = P[4];
    float rr = P[5], rr2 = P[6];

    // density-ratio prescale (D = S_{m+1}^{-1} S_m)
    f1 *= rr; f2 *= rr; f3 *= rr; f4 *= rr2;

    fx2 ra2 = wvno2 - xka2;
    fx2 rb2 = wvno2 - xkb2;
    fx2 ra = v_sqrt(v_abs(ra2));
    fx2 rb = v_sqrt(v_abs(rb2));
    fx2 gam = gammk * wvno2;

    bool px = ra2.x < 0.0f, py = ra2.y < 0.0f;   // propagating P
    bool sx = rb2.x < 0.0f, sy = rb2.y < 0.0f;   // propagating S

    fx2 ra_s = v_max(ra, (fx2)1e-18f);
    fx2 rb_s = v_max(rb, (fx2)1e-18f);
    fx2 rp  = v_rcp(ra_s * rb_s);
    fx2 ira = rb_s * rp;
    fx2 irb = ra_s * rp;

    // ---- P side ----
    fx2 cosp, w, x, fp;
    if (__all(px && py)) {
        fx2 arg = ra * dmsin;
        fx2 s = v_sin(arg);
        cosp = v_cos(arg);
        w = s * ira;
        x = -(ra * s);
        fp = (fx2)1.0f;
    } else if (__all(!px && !py)) {
        fx2 f = v_exp2(ra * dmexp);
        fx2 se = 0.5f - 0.5f * f;
        cosp = 0.5f + 0.5f * f;
        w = se * ira;
        x = ra * se;
        fp = f;
    } else {
        SideVals vx = side_mixed(ra.x, px, dmsin, dmexp, ira.x);
        SideVals vy = side_mixed(ra.y, py, dmsin, dmexp, ira.y);
        cosp.x = vx.cosv; w.x = vx.wv; x.x = vx.xv; fp.x = vx.fv;
        cosp.y = vy.cosv; w.y = vy.wv; x.y = vy.xv; fp.y = vy.fv;
    }

    // ---- S side ----
    fx2 cosq, y, z, fq;
    if (__all(sx && sy)) {
        fx2 arg = rb * dmsin;
        fx2 s = v_sin(arg);
        cosq = v_cos(arg);
        y = s * irb;
        z = -(rb * s);
        fq = (fx2)1.0f;
    } else if (__all(!sx && !sy)) {
        fx2 f = v_exp2(rb * dmexp);
        fx2 se = 0.5f - 0.5f * f;
        cosq = 0.5f + 0.5f * f;
        y = se * irb;
        z = rb * se;
        fq = f;
    } else {
        SideVals vx = side_mixed(rb.x, sx, dmsin, dmexp, irb.x);
        SideVals vy = side_mixed(rb.y, sy, dmsin, dmexp, irb.y);
        cosq.x = vx.cosv; y.x = vx.wv; z.x = vx.xv; fq.x = vx.fv;
        cosq.y = vy.cosv; y.y = vy.wv; z.y = vy.xv; fq.y = vy.fv;
    }

    // a0 = exp(-(pex+sex)) == sqrt(fp*fq)
    fx2 a0 = v_sqrt(fp * fq);

    fx2 cpcq = cosp * cosq;
    fx2 cpy = cosp * y, cpz = cosp * z;
    fx2 cqw = cosq * w, cqx = cosq * x;
    fx2 xy = x * y, xz = x * z, wy = w * y, wz = w * z;

    fx2 gamm1 = gam - 1.0f;
    fx2 twgm1 = gam + gamm1;
    fx2 gmgmk = gam * gammk;
    fx2 gmgm1 = gam * gamm1;
    fx2 gm1sq = gamm1 * gamm1;

    fx2 a0pq  = a0 - cpcq;
    fx2 a0pq2 = a0pq + a0pq;
    fx2 nwy   = wvno2 * wy;
    fx2 gw    = gm1sq * wy;

    // rm-free C' entries (nc* are the negated forms)
    fx2 c00  = cpcq - gmgm1 * a0pq2 - gmgmk * xz - gm1sq * nwy;
    fx2 c01  = wvno2 * cpy - cqx;
    fx2 nc02 = twgm1 * a0pq + gammk * xz + gamm1 * nwy;
    fx2 c03  = cpz - wvno2 * cqw;
    fx2 nc04 = wvno2 * a0pq2 + xz + wvno2 * nwy;
    fx2 c10  = gmgmk * cpz - gm1sq * cqw;
    fx2 c12  = gammk * cpz - gamm1 * cqw;
    fx2 c30  = gm1sq * cpy - gmgmk * cqx;
    fx2 c32  = gamm1 * cpy - gammk * cqx;
    fx2 t40  = gm1sq * a0pq2 + gmgmk * xz;
    fx2 nc40 = gmgmk * t40 + gm1sq * gw;
    fx2 th   = gmgm1 * twgm1;
    fx2 nc42 = th * a0pq + (gmgmk * gammk) * xz + gamm1 * gw;
    fx2 c22  = a0 + 2.0f * (cpcq - c00);

    fx2 e2t = f2 * t2;   // row 2 of C' = t2 * {-nc42, c32, .., c12, -nc02}

    fx2 ee0 =  f0 * c00  + f1 * c10  - e2t * nc42 + f3 * c30  - f4 * nc40;
    fx2 ee1 =  f0 * c01  + f1 * cpcq + e2t * c32  - f3 * xy   + f4 * c30;
    fx2 ee2 = -f0 * nc02 + f1 * c12  + f2 * c22   + f3 * c32  - f4 * nc42;
    fx2 ee3 =  f0 * c03  - f1 * wz   + e2t * c12  + f3 * cpcq + f4 * c10;
    fx2 ee4 = -f0 * nc04 + f1 * c03  - e2t * nc02 + f3 * c01  + f4 * c00;

    if (NORM) {
        fx2 nv = v_max(v_max(v_abs(ee0), v_abs(ee1)), v_max(v_abs(ee2), v_abs(ee3)));
        nv = v_max(nv, v_abs(ee4));
        nv = v_max(nv, (fx2)1e-30f);
        // exact power-of-2 inverse of nrm's exponent (no rcp, no rounding)
        fx2 inv;
        inv.x = __uint_as_float(0x7f000000u - (__float_as_uint(nv.x) & 0x7f800000u));
        inv.y = __uint_as_float(0x7f000000u - (__float_as_uint(nv.y) & 0x7f800000u));
        f0 = ee0 * inv; f1 = ee1 * inv; f2 = ee2 * inv; f3 = ee3 * inv; f4 = ee4 * inv;
    } else {
        f0 = ee0; f1 = ee1; f2 = ee2; f3 = ee3; f4 = ee4;
    }
}

__device__ fx2 det_eval(fx2 cvel, float omega, const float* __restrict__ Lf, float ir0) {
    fx2 wvno  = omega * v_rcp(cvel);
    fx2 wvno2 = wvno * wvno;
    fx2 t2    = -2.0f * wvno2;

    // halfspace (layer NL-1), rho factors dropped (global scale is irrelevant)
    const float* P = &Lf[(NL - 1) * 8];
    fx2 ra = v_sqrt(v_abs(wvno2 - P[0]));
    fx2 rb = v_sqrt(v_abs(wvno2 - P[1]));
    float gammk = P[2];
    fx2 gam = gammk * wvno2;
    fx2 gamm1 = gam - 1.0f;
    fx2 rarb = ra * rb;

    fx2 f0 = gamm1 * gamm1 - gam * gammk * rarb;
    fx2 f1 = -ra;
    fx2 f2 = gamm1 - gammk * rarb;
    fx2 f3 = rb;
    fx2 f4 = wvno2 - rarb;

    // 63 layers: 20 triplets (62..3) with norm on 3rd, then 2,1,0 plain.
    #pragma unroll 1
    for (int m = NL - 2; m >= 5; m -= 3) {
        layer_step<false>(f0, f1, f2, f3, f4, &Lf[m * 8], wvno2, t2);
        layer_step<false>(f0, f1, f2, f3, f4, &Lf[(m - 1) * 8], wvno2, t2);
        layer_step<true >(f0, f1, f2, f3, f4, &Lf[(m - 2) * 8], wvno2, t2);
    }
    layer_step<false>(f0, f1, f2, f3, f4, &Lf[2 * 8], wvno2, t2);
    layer_step<false>(f0, f1, f2, f3, f4, &Lf[1 * 8], wvno2, t2);
    layer_step<false>(f0, f1, f2, f3, f4, &Lf[0 * 8], wvno2, t2);

    // unscale to e-space (S_0 = diag(1, r0, r0, r0, r0^2)) and final max-norm
    fx2 res;
    {
        float m123 = fmaxf(fmaxf(fabsf(f1.x), fabsf(f2.x)), fabsf(f3.x)) * ir0;
        float nrm = fmaxf(fabsf(f0.x), fmaxf(m123, fabsf(f4.x) * (ir0 * ir0)));
        res.x = f0.x * hrcp(nrm);
    }
    {
        float m123 = fmaxf(fmaxf(fabsf(f1.y), fabsf(f2.y)), fabsf(f3.y)) * ir0;
        float nrm = fmaxf(fabsf(f0.y), fmaxf(m123, fabsf(f4.y) * (ir0 * ir0)));
        res.y = f0.y * hrcp(nrm);
    }
    return res;
}

// ---------------------------------------------------------------------------
// Kernel 2: two dets per thread (packed); wave-reduce max/min; atomics per wave.
// grid = (NCHUNK, NOBS), block = 128. idx==HALF_NC is the (vlist[t]) sentinel.
// ---------------------------------------------------------------------------
__global__ __launch_bounds__(128, 2) void det_kernel(
    const float* __restrict__ vlist, const float* __restrict__ tlist,
    const float* __restrict__ d, const float* __restrict__ b,
    const float* __restrict__ Clist,
    const float* __restrict__ a_arr, const float* __restrict__ rho_arr,
    unsigned* __restrict__ maxenc, unsigned* __restrict__ minenc,
    float* __restrict__ e00vals) {

    __shared__ float Lf[NL * 8];
    __shared__ float s_ir0;

    int t     = blockIdx.y;
    int chunk = blockIdx.x;
    int tid   = threadIdx.x;

    float omega = fmaxf(TWO_PI_F / tlist[t], 0.0001f);

    if (tid < NL) {
        float am = a_arr[tid];
        float bm = b[tid];
        float dm = d[tid];
        float* P = &Lf[tid * 8];
        float ta = omega / am;
        float tb = omega / bm;
        P[0] = ta * ta;
        P[1] = tb * tb;
        float tt = bm / omega;
        P[2] = 2.0f * tt * tt;
        P[3] = dm * INV_2PI_F;
        P[4] = -2.0f * LOG2E_F * dm;
        float rr = (tid < NL - 1) ? (rho_arr[tid] / rho_arr[tid + 1]) : 1.0f;
        P[5] = rr;
        P[6] = rr * rr;
        P[7] = 0.0f;
        if (tid == 0) s_ir0 = 1.0f / rho_arr[0];
    }
    __syncthreads();

    int idx = chunk * CHUNK + tid;
    float lmax = -FLT_MAX, lmin = FLT_MAX;

    if (idx <= HALF_NC) {
        bool grid_pt = idx < HALF_NC;
        fx2 cv;
        if (grid_pt) { cv.x = Clist[idx]; cv.y = Clist[idx + HALF_NC]; }
        else         { cv.x = vlist[t];   cv.y = cv.x; }
        fx2 det = det_eval(cv, omega, Lf, s_ir0);
        if (grid_pt) {
            lmax = fmaxf(det.x, det.y);
            lmin = fminf(det.x, det.y);
        } else {
            e00vals[t] = det.x;
        }
    }

    // wave-level butterfly reduce (64 lanes)
    #pragma unroll
    for (int off = 32; off >= 1; off >>= 1) {
        lmax = fmaxf(lmax, __shfl_xor(lmax, off));
        lmin = fminf(lmin, __shfl_xor(lmin, off));
    }
    if ((tid & 63) == 0) {
        atomicMax(&maxenc[t], enc(lmax));
        atomicMin(&minenc[t], enc(lmin));
    }
}

// ---------------------------------------------------------------------------
// Kernel 3: combine, misfit transform, damping, final sum
// ---------------------------------------------------------------------------
__global__ __launch_bounds__(512) void finalize_kernel(
    const float* __restrict__ b,
    const unsigned* __restrict__ maxenc, const unsigned* __restrict__ minenc,
    const float* __restrict__ e00vals, float* __restrict__ out) {

    int tid = threadIdx.x;
    float acc = 0.0f;

    if (tid < NOBS) {
        float mx = dec(maxenc[tid]);
        float mn = dec(minenc[tid]);
        float rng  = mx - mn;
        float e00  = e00vals[tid] / rng;
        float term = exp2f(LOG2_0P1 * fabsf(e00)) - 1.0f;  // 0.1^|e00| - 1
        acc = fabsf(term) * (1.0f / (float)NOBS);
    }
    if (tid < NL) {
        float bi = b[tid];
        float lb;
        if (tid == 0)            lb = bi - b[1];
        else if (tid == NL - 1)  lb = bi - b[NL - 2];
        else                     lb = 2.0f * bi - b[tid - 1] - b[tid + 1];
        acc += fabsf(lb * (1.0f / (float)NL));   // DAMP = 1.0
    }

    __shared__ float s[512];
    s[tid] = acc;
    __syncthreads();
    for (int st = 256; st > 0; st >>= 1) {
        if (tid < st) s[tid] += s[tid + st];
        __syncthreads();
    }
    if (tid == 0) out[0] = s[0];
}

// ---------------------------------------------------------------------------
extern "C" void kernel_launch(void* const* d_in, const int* in_sizes, int n_in,
                              void* d_out, int out_size, void* d_ws, size_t ws_size,
                              hipStream_t stream) {
    const float* vlist = (const float*)d_in[0];
    const float* tlist = (const float*)d_in[1];
    const float* d     = (const float*)d_in[2];
    const float* b     = (const float*)d_in[3];
    const float* Clist = (const float*)d_in[4];
    float* out = (float*)d_out;

    float*    ws      = (float*)d_ws;
    float*    a_arr   = ws;                       // 64
    float*    rho_arr = ws + 64;                  // 64
    float*    e00v    = ws + 128;                 // 400
    unsigned* maxenc  = (unsigned*)(ws + 528);    // 400
    unsigned* minenc  = (unsigned*)(ws + 928);    // 400   (total ~5.3 KB)

    prep_kernel<<<1, 256, 0, stream>>>(b, a_arr, rho_arr, maxenc, minenc);
    det_kernel<<<dim3(NCHUNK, NOBS), 128, 0, stream>>>(vlist, tlist, d, b, Clist,
                                                       a_arr, rho_arr, maxenc, minenc, e00v);
    finalize_kernel<<<1, 512, 0, stream>>>(b, maxenc, minenc, e00v, out);
}